// Round 9
// baseline (411.025 us; speedup 1.0000x reference)
//
#include <hip/hip_runtime.h>
#include <hip/hip_bf16.h>
#include <stdint.h>

#define MEM_DIM 128
#define MSG_DIM 256
#define KTOT    384          // MSG_DIM + MEM_DIM
#define BM      64           // update rows per block

typedef __attribute__((ext_vector_type(8))) __bf16 bf16x8;
typedef __attribute__((ext_vector_type(4))) float  f32x4;

union B8u { uint32_t u[4]; bf16x8 v; };

__device__ __forceinline__ uint32_t cvt_pk(float lo, float hi) {
    uint32_t r;
    asm("v_cvt_pk_bf16_f32 %0, %1, %2" : "=v"(r) : "v"(lo), "v"(hi));
    return r;
}

__device__ __forceinline__ bf16x8 load_cvt8(const float* __restrict__ p) {
    f32x4 a = *(const f32x4*)p;
    f32x4 b = *(const f32x4*)(p + 4);
    B8u r;
    r.u[0] = cvt_pk(a.x, a.y);
    r.u[1] = cvt_pk(a.z, a.w);
    r.u[2] = cvt_pk(b.x, b.y);
    r.u[3] = cvt_pk(b.z, b.w);
    return r.v;
}

__device__ __forceinline__ float sigm(float x) {
    return __builtin_amdgcn_rcpf(1.0f + __expf(-x));
}
__device__ __forceinline__ float tanh_fast(float x) {
    return 1.0f - 2.0f * __builtin_amdgcn_rcpf(1.0f + __expf(2.0f * x));
}

// --------------------------------------------- bitmap + counter init kernels
__global__ void bm_zero_kernel(uint32_t* __restrict__ bm, int nwords) {
    int i = blockIdx.x * 256 + threadIdx.x;
    if (i < nwords) bm[i] = 0;          // includes the work-steal counter word
}
__global__ void bm_set_kernel(const int* __restrict__ ids, uint32_t* __restrict__ bm, int U) {
    int i = blockIdx.x * 256 + threadIdx.x;
    if (i < U) {
        int id = ids[i];
        atomicOr(&bm[id >> 5], 1u << (id & 31));
    }
}

// ------------------------------------------------------- weight bf16 convert
__global__ void wconv_kernel(const float* __restrict__ wih,
                             const float* __restrict__ whh,
                             __hip_bfloat16* __restrict__ out) {
    int i = blockIdx.x * 256 + threadIdx.x;
    const int NIH = 3 * MEM_DIM * MSG_DIM;   // 98304
    const int NHH = 3 * MEM_DIM * MEM_DIM;   // 49152
    if (i < NIH)            out[i] = __float2bfloat16(wih[i]);
    else if (i < NIH + NHH) out[i] = __float2bfloat16(whh[i - NIH]);
}

// fallback kernels (no workspace)
__global__ void copy_all_kernel(const f32x4* __restrict__ mem,
                                const f32x4* __restrict__ lu,
                                f32x4* __restrict__ out,
                                int n_mem4, int n_tot4) {
    int stride = gridDim.x * blockDim.x;
    for (int i = blockIdx.x * blockDim.x + threadIdx.x; i < n_tot4; i += stride) {
        f32x4 v = (i < n_mem4) ? mem[i]
                               : __builtin_nontemporal_load(&lu[i - n_mem4]);
        __builtin_nontemporal_store(v, &out[i]);
    }
}

// ------------------------------------------------------ fused GRU + copy
// Role interleave: of each group of 4 blocks, 3 run one GEMM tile then join
// the copy; the 4th copies immediately -> CUs host a mix of latency-bound
// (GEMM) and BW-bound (copy) waves from t=0 (m114 co-schedule). Copy work is
// distributed via an atomic work-steal counter so late joiners cause no tail.
__device__ __forceinline__ int at_addr(int row, int kbyte) {
    return (row * (KTOT * 2) + kbyte) ^ ((row & 7) << 4);
}

#define BATCH_CHUNKS (512 * 16)   // 8192 x 16B = 128 KB per stolen batch

template<bool PRE>
__global__ __launch_bounds__(512, 4)
void gru_copy_kernel(const float* __restrict__ memory,
                     const int*   __restrict__ ids,
                     const float* __restrict__ msgs,
                     const float* __restrict__ ts,
                     const float* __restrict__ Wih,
                     const float* __restrict__ Whh,
                     const float* __restrict__ bih,
                     const float* __restrict__ bhh,
                     const __hip_bfloat16* __restrict__ WihB,  // [384][256]
                     const __hip_bfloat16* __restrict__ WhhB,  // [384][128]
                     const uint32_t* __restrict__ bm,
                     uint32_t* __restrict__ ctr,
                     const float* __restrict__ last_update,
                     float* __restrict__ out_mem,
                     float* __restrict__ out_lu,
                     int U, int ntiles, int NN) {
    __shared__ __align__(16) char At[BM * KTOT * 2];   // 49152 B
    __shared__ uint32_t sbatch;

    const int tid  = threadIdx.x;
    const int bid  = blockIdx.x;
    const int grp  = bid >> 2, role = bid & 3;
    const int t    = grp * 3 + role;                   // tile index (roles 0..2)

    if (role != 3 && t < ntiles) {
        // ================= GEMM tile =================
        const int w    = tid >> 6;
        const int lane = tid & 63;
        const int lq   = lane & 15;
        const int lk   = lane >> 4;
        const int rb   = t * BM;

        if (tid < BM) {
            int r = rb + tid;
            if (r < U) out_lu[ids[r]] = ts[r];
        }
        {   // stage At: x part
            int r = tid >> 3, seg = tid & 7;
            int rA = rb + r; if (rA >= U) rA = U - 1;
            const float* xp = msgs + (size_t)rA * MSG_DIM + seg * 32;
            #pragma unroll
            for (int i = 0; i < 4; ++i)
                *(bf16x8*)(At + at_addr(r, seg * 64 + i * 16)) = load_cvt8(xp + i * 8);
        }
        {   // stage At: h part
            int r = tid >> 3, u = tid & 7;
            int rA = rb + r; if (rA >= U) rA = U - 1;
            const float* hp = memory + (size_t)ids[rA] * MEM_DIM + u * 16;
            *(bf16x8*)(At + at_addr(r, 512 + u * 32))      = load_cvt8(hp);
            *(bf16x8*)(At + at_addr(r, 512 + u * 32 + 16)) = load_cvt8(hp + 8);
        }

        const int c = w * 16 + lq;
        const float br  = bih[c] + bhh[c];
        const float bz  = bih[MEM_DIM + c] + bhh[MEM_DIM + c];
        const float bin = bih[2 * MEM_DIM + c];
        const float bhn = bhh[2 * MEM_DIM + c];

        const __hip_bfloat16* wih_l = WihB + c * MSG_DIM + lk * 8;
        const __hip_bfloat16* whh_l = WhhB + c * MEM_DIM + lk * 8;
        const float* wih_f = Wih + c * MSG_DIM + lk * 8;
        const float* whh_f = Whh + c * MEM_DIM + lk * 8;

        const f32x4 z4 = {0.f, 0.f, 0.f, 0.f};
        f32x4 acc[4][4];
        #pragma unroll
        for (int m = 0; m < 4; ++m)
            #pragma unroll
            for (int q = 0; q < 4; ++q) acc[m][q] = z4;

        __syncthreads();   // At ready

        // phase X: W_ih, 8 k-steps, gates r,z,i_n
        #pragma unroll 1
        for (int ks = 0; ks < 8; ++ks) {
            bf16x8 bv0, bv1, bv2;
            if (PRE) {
                bv0 = *(const bf16x8*)(wih_l + 0 * 128 * MSG_DIM + ks * 32);
                bv1 = *(const bf16x8*)(wih_l + 1 * 128 * MSG_DIM + ks * 32);
                bv2 = *(const bf16x8*)(wih_l + 2 * 128 * MSG_DIM + ks * 32);
            } else {
                bv0 = load_cvt8(wih_f + 0 * 128 * MSG_DIM + ks * 32);
                bv1 = load_cvt8(wih_f + 1 * 128 * MSG_DIM + ks * 32);
                bv2 = load_cvt8(wih_f + 2 * 128 * MSG_DIM + ks * 32);
            }
            bf16x8 af[4];
            #pragma unroll
            for (int m = 0; m < 4; ++m)
                af[m] = *(const bf16x8*)(At + at_addr(m * 16 + lq, ks * 64 + lk * 16));
            #pragma unroll
            for (int m = 0; m < 4; ++m)
                acc[m][0] = __builtin_amdgcn_mfma_f32_16x16x32_bf16(af[m], bv0, acc[m][0], 0, 0, 0);
            #pragma unroll
            for (int m = 0; m < 4; ++m)
                acc[m][1] = __builtin_amdgcn_mfma_f32_16x16x32_bf16(af[m], bv1, acc[m][1], 0, 0, 0);
            #pragma unroll
            for (int m = 0; m < 4; ++m)
                acc[m][2] = __builtin_amdgcn_mfma_f32_16x16x32_bf16(af[m], bv2, acc[m][2], 0, 0, 0);
        }
        // phase H: W_hh, 4 k-steps, gates r,z,h_n
        #pragma unroll 1
        for (int ks = 0; ks < 4; ++ks) {
            bf16x8 bv0, bv1, bv2;
            if (PRE) {
                bv0 = *(const bf16x8*)(whh_l + 0 * 128 * MEM_DIM + ks * 32);
                bv1 = *(const bf16x8*)(whh_l + 1 * 128 * MEM_DIM + ks * 32);
                bv2 = *(const bf16x8*)(whh_l + 2 * 128 * MEM_DIM + ks * 32);
            } else {
                bv0 = load_cvt8(whh_f + 0 * 128 * MEM_DIM + ks * 32);
                bv1 = load_cvt8(whh_f + 1 * 128 * MEM_DIM + ks * 32);
                bv2 = load_cvt8(whh_f + 2 * 128 * MEM_DIM + ks * 32);
            }
            bf16x8 af[4];
            #pragma unroll
            for (int m = 0; m < 4; ++m)
                af[m] = *(const bf16x8*)(At + at_addr(m * 16 + lq, 512 + ks * 64 + lk * 16));
            #pragma unroll
            for (int m = 0; m < 4; ++m)
                acc[m][0] = __builtin_amdgcn_mfma_f32_16x16x32_bf16(af[m], bv0, acc[m][0], 0, 0, 0);
            #pragma unroll
            for (int m = 0; m < 4; ++m)
                acc[m][1] = __builtin_amdgcn_mfma_f32_16x16x32_bf16(af[m], bv1, acc[m][1], 0, 0, 0);
            #pragma unroll
            for (int m = 0; m < 4; ++m)
                acc[m][3] = __builtin_amdgcn_mfma_f32_16x16x32_bf16(af[m], bv2, acc[m][3], 0, 0, 0);
        }

        // epilogue
        #pragma unroll
        for (int m = 0; m < 4; ++m) {
            #pragma unroll
            for (int j = 0; j < 4; ++j) {
                int row = m * 16 + lk * 4 + j;
                int r = rb + row;
                if (r < U) {
                    int id = ids[r];
                    float hold = __bfloat162float(
                        *(const __hip_bfloat16*)(At + at_addr(row, 512 + c * 2)));
                    float rg = sigm(acc[m][0][j] + br);
                    float zg = sigm(acc[m][1][j] + bz);
                    float ng = tanh_fast(acc[m][2][j] + bin + rg * (acc[m][3][j] + bhn));
                    __builtin_nontemporal_store((1.0f - zg) * ng + zg * hold,
                                                &out_mem[(size_t)id * MEM_DIM + c]);
                }
            }
        }
    }

    // ================= work-stealing passthrough copy =================
    const int64_t n_mem_chunks = (int64_t)NN * 32;        // 512 B rows / 16 B
    const int64_t n_lu_chunks  = (NN + 3) >> 2;           // 4 floats / 16 B
    const int64_t total_chunks = n_mem_chunks + n_lu_chunks;
    const f32x4* memv = (const f32x4*)memory;
    f32x4* outv = (f32x4*)out_mem;

    for (;;) {
        __syncthreads();
        if (tid == 0) sbatch = atomicAdd(ctr, 1u);
        __syncthreads();
        int64_t base = (int64_t)sbatch * BATCH_CHUNKS;
        if (base >= total_chunks) break;
        #pragma unroll
        for (int k = 0; k < 16; ++k) {
            int64_t i = base + k * 512 + tid;
            if (i < n_mem_chunks) {
                int row = (int)(i >> 5);
                if (!((bm[row >> 5] >> (row & 31)) & 1u)) {
                    f32x4 v = __builtin_nontemporal_load(&memv[i]);
                    __builtin_nontemporal_store(v, &outv[i]);
                }
            } else if (i < total_chunks) {
                int node = (int)(i - n_mem_chunks) * 4;
                #pragma unroll
                for (int j = 0; j < 4; ++j) {
                    int n = node + j;
                    if (n < NN && !((bm[n >> 5] >> (n & 31)) & 1u))
                        out_lu[n] = last_update[n];
                }
            }
        }
    }
}

// ------------------------------------------------------------------- launcher
extern "C" void kernel_launch(void* const* d_in, const int* in_sizes, int n_in,
                              void* d_out, int out_size, void* d_ws, size_t ws_size,
                              hipStream_t stream) {
    const float* memory      = (const float*)d_in[0];
    const float* last_update = (const float*)d_in[1];
    const int*   ids         = (const int*)  d_in[2];
    const float* msgs        = (const float*)d_in[3];
    const float* ts          = (const float*)d_in[4];
    const float* Wih         = (const float*)d_in[5];
    const float* Whh         = (const float*)d_in[6];
    const float* bih         = (const float*)d_in[7];
    const float* bhh         = (const float*)d_in[8];

    const int NN = in_sizes[1];          // 1,000,000 nodes
    const int U  = in_sizes[2];          // 200,000 updates

    float* out_mem = (float*)d_out;
    float* out_lu  = out_mem + (size_t)NN * MEM_DIM;

    const int NIH = 3 * MEM_DIM * MSG_DIM;                    // 98304
    const int NHH = 3 * MEM_DIM * MEM_DIM;                    // 49152
    const size_t WBYTES  = (size_t)(NIH + NHH) * sizeof(__hip_bfloat16);  // 294912
    const size_t BM_OFF  = (WBYTES + 255) & ~(size_t)255;
    const int    BMWORDS = (NN + 31) / 32;
    const int    ntiles  = (U + BM - 1) / BM;                 // 3125
    const int    ngrp    = (ntiles + 2) / 3;
    const int    GRID    = ngrp * 4;                          // 3:1 gemm:copy roles

    if (ws_size >= BM_OFF + (size_t)(BMWORDS + 1) * 4) {
        __hip_bfloat16* wb = (__hip_bfloat16*)d_ws;
        uint32_t* bm  = (uint32_t*)((char*)d_ws + BM_OFF);
        uint32_t* ctr = bm + BMWORDS;

        wconv_kernel<<<(NIH + NHH + 255) / 256, 256, 0, stream>>>(Wih, Whh, wb);
        bm_zero_kernel<<<(BMWORDS + 1 + 255) / 256, 256, 0, stream>>>(bm, BMWORDS + 1);
        bm_set_kernel<<<(U + 255) / 256, 256, 0, stream>>>(ids, bm, U);

        gru_copy_kernel<true><<<GRID, 512, 0, stream>>>(
            memory, ids, msgs, ts, Wih, Whh, bih, bhh,
            wb, wb + NIH, bm, ctr, last_update, out_mem, out_lu, U, ntiles, NN);
    } else {
        // fallback: full copy then GRU overwrite (no bitmap, no counter)
        int n_mem4 = NN * MEM_DIM / 4;
        int n_tot4 = n_mem4 + NN / 4;
        copy_all_kernel<<<8192, 256, 0, stream>>>((const f32x4*)memory,
                                                  (const f32x4*)last_update,
                                                  (f32x4*)d_out, n_mem4, n_tot4);
        // reuse fused kernel with ntiles tiles only (copy part disabled via ctr==nullptr
        // not possible) -> simple dedicated path: launch with a dummy counter is not
        // available, so run the GEMM via the same kernel with GRID covering tiles and
        // total_chunks==0 by passing NN=0 for the copy phase.
        gru_copy_kernel<false><<<((U + BM - 1) / BM + 2) / 3 * 4, 512, 0, stream>>>(
            memory, ids, msgs, ts, Wih, Whh, bih, bhh,
            nullptr, nullptr, nullptr, (uint32_t*)d_ws, last_update,
            out_mem, out_lu, U, (U + BM - 1) / BM, 0);
    }
}

// Round 10
// 364.677 us; speedup vs baseline: 1.1271x; 1.1271x over previous
//
#include <hip/hip_runtime.h>
#include <hip/hip_bf16.h>
#include <stdint.h>

#define MEM_DIM 128
#define MSG_DIM 256
#define KTOT    384          // MSG_DIM + MEM_DIM
#define BM      64           // update rows per block

typedef __attribute__((ext_vector_type(8))) __bf16 bf16x8;
typedef __attribute__((ext_vector_type(4))) float  f32x4;

union B8u { uint32_t u[4]; bf16x8 v; };

__device__ __forceinline__ uint32_t cvt_pk(float lo, float hi) {
    uint32_t r;
    asm("v_cvt_pk_bf16_f32 %0, %1, %2" : "=v"(r) : "v"(lo), "v"(hi));
    return r;
}

__device__ __forceinline__ bf16x8 load_cvt8(const float* __restrict__ p) {
    f32x4 a = *(const f32x4*)p;
    f32x4 b = *(const f32x4*)(p + 4);
    B8u r;
    r.u[0] = cvt_pk(a.x, a.y);
    r.u[1] = cvt_pk(a.z, a.w);
    r.u[2] = cvt_pk(b.x, b.y);
    r.u[3] = cvt_pk(b.z, b.w);
    return r.v;
}

__device__ __forceinline__ float sigm(float x) {
    return __builtin_amdgcn_rcpf(1.0f + __expf(-x));
}
__device__ __forceinline__ float tanh_fast(float x) {
    return 1.0f - 2.0f * __builtin_amdgcn_rcpf(1.0f + __expf(2.0f * x));
}

// ------------------------------------------------------------- bitmap kernels
__global__ void bm_zero_kernel(uint32_t* __restrict__ bm, int nwords) {
    int i = blockIdx.x * 256 + threadIdx.x;
    if (i < nwords) bm[i] = 0;
}
__global__ void bm_set_kernel(const int* __restrict__ ids, uint32_t* __restrict__ bm, int U) {
    int i = blockIdx.x * 256 + threadIdx.x;
    if (i < U) {
        int id = ids[i];
        atomicOr(&bm[id >> 5], 1u << (id & 31));
    }
}

// ------------------------------------------------------- weight bf16 convert
__global__ void wconv_kernel(const float* __restrict__ wih,
                             const float* __restrict__ whh,
                             __hip_bfloat16* __restrict__ out) {
    int i = blockIdx.x * 256 + threadIdx.x;
    const int NIH = 3 * MEM_DIM * MSG_DIM;   // 98304
    const int NHH = 3 * MEM_DIM * MEM_DIM;   // 49152
    if (i < NIH)            out[i] = __float2bfloat16(wih[i]);
    else if (i < NIH + NHH) out[i] = __float2bfloat16(whh[i - NIH]);
}

// ----------------------------------------------- copy kernel (skips updated)
__global__ void copy_skip_kernel(const f32x4* __restrict__ mem,
                                 const float* __restrict__ lu,
                                 f32x4* __restrict__ outm,
                                 float* __restrict__ outlu,
                                 const uint32_t* __restrict__ bm,
                                 int NN) {
    const int64_t n_mem_chunks = (int64_t)NN * 32;   // 512 B rows / 16 B
    const int64_t total = n_mem_chunks + NN;
    const int64_t stride = (int64_t)gridDim.x * blockDim.x;
    for (int64_t i = (int64_t)blockIdx.x * blockDim.x + threadIdx.x; i < total; i += stride) {
        if (i < n_mem_chunks) {
            int row = (int)(i >> 5);
            if (!((bm[row >> 5] >> (row & 31)) & 1u)) {
                f32x4 v = __builtin_nontemporal_load(&mem[i]);
                __builtin_nontemporal_store(v, &outm[i]);
            }
        } else {
            int node = (int)(i - n_mem_chunks);
            if (!((bm[node >> 5] >> (node & 31)) & 1u))
                outlu[node] = lu[node];
        }
    }
}

// fallback full copy (no workspace for bitmap)
__global__ void copy_all_kernel(const f32x4* __restrict__ mem,
                                const f32x4* __restrict__ lu,
                                f32x4* __restrict__ out,
                                int n_mem4, int n_tot4) {
    int stride = gridDim.x * blockDim.x;
    for (int i = blockIdx.x * blockDim.x + threadIdx.x; i < n_tot4; i += stride) {
        f32x4 v = (i < n_mem4) ? mem[i]
                               : __builtin_nontemporal_load(&lu[i - n_mem4]);
        __builtin_nontemporal_store(v, &out[i]);
    }
}

// ---------------------------------------------------------------- stream GRU
// Block: 512 threads = 8 waves, BM=64 rows. At[64][384] bf16 in LDS (staged
// once, XOR-swizzled). B fragments stream global->MFMA with a DEPTH-1
// SOFTWARE PIPELINE: next k-step's 3 fragments are issued before the current
// MFMAs, hiding L2 latency under compute. No Bt LDS, no per-K-step barriers.
__device__ __forceinline__ int at_addr(int row, int kbyte) {
    return (row * (KTOT * 2) + kbyte) ^ ((row & 7) << 4);
}

template<bool PRE>
__global__ __launch_bounds__(512, 4)
void gru_stream_kernel(const float* __restrict__ memory,
                       const int*   __restrict__ ids,
                       const float* __restrict__ msgs,
                       const float* __restrict__ ts,
                       const float* __restrict__ Wih,
                       const float* __restrict__ Whh,
                       const float* __restrict__ bih,
                       const float* __restrict__ bhh,
                       const __hip_bfloat16* __restrict__ WihB,  // [384][256]
                       const __hip_bfloat16* __restrict__ WhhB,  // [384][128]
                       float* __restrict__ out_mem,
                       float* __restrict__ out_lu,
                       int U) {
    __shared__ __align__(16) char At[BM * KTOT * 2];   // 49152 B

    const int tid  = threadIdx.x;
    const int w    = tid >> 6;
    const int lane = tid & 63;
    const int lq   = lane & 15;
    const int lk   = lane >> 4;
    const int rb   = blockIdx.x * BM;

    // ---- timestamp scatter
    if (tid < BM) {
        int r = rb + tid;
        if (r < U) out_lu[ids[r]] = ts[r];
    }

    // ---- stage At: x part (512 threads, 8 segs of 32 f32 per row)
    {
        int r = tid >> 3, seg = tid & 7;
        int rA = rb + r; if (rA >= U) rA = U - 1;
        const float* xp = msgs + (size_t)rA * MSG_DIM + seg * 32;
        #pragma unroll
        for (int i = 0; i < 4; ++i)
            *(bf16x8*)(At + at_addr(r, seg * 64 + i * 16)) = load_cvt8(xp + i * 8);
    }
    // ---- stage At: h part (512 threads, 8 units of 16 f32 per row)
    {
        int r = tid >> 3, u = tid & 7;
        int rA = rb + r; if (rA >= U) rA = U - 1;
        const float* hp = memory + (size_t)ids[rA] * MEM_DIM + u * 16;
        *(bf16x8*)(At + at_addr(r, 512 + u * 32))      = load_cvt8(hp);
        *(bf16x8*)(At + at_addr(r, 512 + u * 32 + 16)) = load_cvt8(hp + 8);
    }

    // this lane's output column + biases
    const int c = w * 16 + lq;
    const float br  = bih[c] + bhh[c];
    const float bz  = bih[MEM_DIM + c] + bhh[MEM_DIM + c];
    const float bin = bih[2 * MEM_DIM + c];
    const float bhn = bhh[2 * MEM_DIM + c];

    // per-lane weight base pointers
    const __hip_bfloat16* wih_l = WihB + c * MSG_DIM + lk * 8;
    const __hip_bfloat16* whh_l = WhhB + c * MEM_DIM + lk * 8;
    const float* wih_f = Wih + c * MSG_DIM + lk * 8;
    const float* whh_f = Whh + c * MEM_DIM + lk * 8;

    const f32x4 z4 = {0.f, 0.f, 0.f, 0.f};
    f32x4 acc[4][4];
    #pragma unroll
    for (int m = 0; m < 4; ++m)
        #pragma unroll
        for (int q = 0; q < 4; ++q) acc[m][q] = z4;

    // prime the pipeline: B fragments for X k-step 0 (issued BEFORE the
    // barrier so the load overlaps the At staging drain)
    bf16x8 cb0, cb1, cb2;
    if (PRE) {
        cb0 = *(const bf16x8*)(wih_l + 0 * 128 * MSG_DIM);
        cb1 = *(const bf16x8*)(wih_l + 1 * 128 * MSG_DIM);
        cb2 = *(const bf16x8*)(wih_l + 2 * 128 * MSG_DIM);
    } else {
        cb0 = load_cvt8(wih_f + 0 * 128 * MSG_DIM);
        cb1 = load_cvt8(wih_f + 1 * 128 * MSG_DIM);
        cb2 = load_cvt8(wih_f + 2 * 128 * MSG_DIM);
    }

    __syncthreads();   // At ready

    // ---------------- phase X: W_ih, 8 k-steps, gates r,z,i_n
    #pragma unroll 1
    for (int ks = 0; ks < 8; ++ks) {
        // prefetch next slice (k-step ks+1; on ks==7 prefetch H slice 0)
        bf16x8 nb0, nb1, nb2;
        if (ks < 7) {
            const int o = (ks + 1) * 32;
            if (PRE) {
                nb0 = *(const bf16x8*)(wih_l + 0 * 128 * MSG_DIM + o);
                nb1 = *(const bf16x8*)(wih_l + 1 * 128 * MSG_DIM + o);
                nb2 = *(const bf16x8*)(wih_l + 2 * 128 * MSG_DIM + o);
            } else {
                nb0 = load_cvt8(wih_f + 0 * 128 * MSG_DIM + o);
                nb1 = load_cvt8(wih_f + 1 * 128 * MSG_DIM + o);
                nb2 = load_cvt8(wih_f + 2 * 128 * MSG_DIM + o);
            }
        } else {
            if (PRE) {
                nb0 = *(const bf16x8*)(whh_l + 0 * 128 * MEM_DIM);
                nb1 = *(const bf16x8*)(whh_l + 1 * 128 * MEM_DIM);
                nb2 = *(const bf16x8*)(whh_l + 2 * 128 * MEM_DIM);
            } else {
                nb0 = load_cvt8(whh_f + 0 * 128 * MEM_DIM);
                nb1 = load_cvt8(whh_f + 1 * 128 * MEM_DIM);
                nb2 = load_cvt8(whh_f + 2 * 128 * MEM_DIM);
            }
        }
        bf16x8 af[4];
        #pragma unroll
        for (int m = 0; m < 4; ++m)
            af[m] = *(const bf16x8*)(At + at_addr(m * 16 + lq, ks * 64 + lk * 16));
        #pragma unroll
        for (int m = 0; m < 4; ++m)
            acc[m][0] = __builtin_amdgcn_mfma_f32_16x16x32_bf16(af[m], cb0, acc[m][0], 0, 0, 0);
        #pragma unroll
        for (int m = 0; m < 4; ++m)
            acc[m][1] = __builtin_amdgcn_mfma_f32_16x16x32_bf16(af[m], cb1, acc[m][1], 0, 0, 0);
        #pragma unroll
        for (int m = 0; m < 4; ++m)
            acc[m][2] = __builtin_amdgcn_mfma_f32_16x16x32_bf16(af[m], cb2, acc[m][2], 0, 0, 0);
        cb0 = nb0; cb1 = nb1; cb2 = nb2;
    }
    // ---------------- phase H: W_hh, 4 k-steps, gates r,z,h_n
    #pragma unroll 1
    for (int ks = 0; ks < 4; ++ks) {
        // prefetch next H slice (clamped on the last iteration: harmless
        // redundant in-bounds load, keeps the pipeline code uniform)
        const int kn = (ks < 3) ? (ks + 1) : 3;
        bf16x8 nb0, nb1, nb2;
        {
            const int o = kn * 32;
            if (PRE) {
                nb0 = *(const bf16x8*)(whh_l + 0 * 128 * MEM_DIM + o);
                nb1 = *(const bf16x8*)(whh_l + 1 * 128 * MEM_DIM + o);
                nb2 = *(const bf16x8*)(whh_l + 2 * 128 * MEM_DIM + o);
            } else {
                nb0 = load_cvt8(whh_f + 0 * 128 * MEM_DIM + o);
                nb1 = load_cvt8(whh_f + 1 * 128 * MEM_DIM + o);
                nb2 = load_cvt8(whh_f + 2 * 128 * MEM_DIM + o);
            }
        }
        bf16x8 af[4];
        #pragma unroll
        for (int m = 0; m < 4; ++m)
            af[m] = *(const bf16x8*)(At + at_addr(m * 16 + lq, 512 + ks * 64 + lk * 16));
        #pragma unroll
        for (int m = 0; m < 4; ++m)
            acc[m][0] = __builtin_amdgcn_mfma_f32_16x16x32_bf16(af[m], cb0, acc[m][0], 0, 0, 0);
        #pragma unroll
        for (int m = 0; m < 4; ++m)
            acc[m][1] = __builtin_amdgcn_mfma_f32_16x16x32_bf16(af[m], cb1, acc[m][1], 0, 0, 0);
        #pragma unroll
        for (int m = 0; m < 4; ++m)
            acc[m][3] = __builtin_amdgcn_mfma_f32_16x16x32_bf16(af[m], cb2, acc[m][3], 0, 0, 0);
        cb0 = nb0; cb1 = nb1; cb2 = nb2;
    }

    // ---- epilogue: gate math + scatter (h_old read back from At)
    #pragma unroll
    for (int m = 0; m < 4; ++m) {
        #pragma unroll
        for (int j = 0; j < 4; ++j) {
            int row = m * 16 + lk * 4 + j;
            int r = rb + row;
            if (r < U) {
                int id = ids[r];
                float hold = __bfloat162float(
                    *(const __hip_bfloat16*)(At + at_addr(row, 512 + c * 2)));
                float rg = sigm(acc[m][0][j] + br);
                float zg = sigm(acc[m][1][j] + bz);
                float ng = tanh_fast(acc[m][2][j] + bin + rg * (acc[m][3][j] + bhn));
                out_mem[(size_t)id * MEM_DIM + c] = (1.0f - zg) * ng + zg * hold;
            }
        }
    }
}

// ------------------------------------------------------------------- launcher
extern "C" void kernel_launch(void* const* d_in, const int* in_sizes, int n_in,
                              void* d_out, int out_size, void* d_ws, size_t ws_size,
                              hipStream_t stream) {
    const float* memory      = (const float*)d_in[0];
    const float* last_update = (const float*)d_in[1];
    const int*   ids         = (const int*)  d_in[2];
    const float* msgs        = (const float*)d_in[3];
    const float* ts          = (const float*)d_in[4];
    const float* Wih         = (const float*)d_in[5];
    const float* Whh         = (const float*)d_in[6];
    const float* bih         = (const float*)d_in[7];
    const float* bhh         = (const float*)d_in[8];

    const int NN = in_sizes[1];          // 1,000,000 nodes
    const int U  = in_sizes[2];          // 200,000 updates

    float* out_mem = (float*)d_out;
    float* out_lu  = out_mem + (size_t)NN * MEM_DIM;

    const int NIH = 3 * MEM_DIM * MSG_DIM;                    // 98304
    const int NHH = 3 * MEM_DIM * MEM_DIM;                    // 49152
    const size_t WBYTES  = (size_t)(NIH + NHH) * sizeof(__hip_bfloat16);  // 294912
    const size_t BM_OFF  = (WBYTES + 255) & ~(size_t)255;
    const int    BMWORDS = (NN + 31) / 32;
    const int    nblocks = (U + BM - 1) / BM;                 // 3125

    if (ws_size >= BM_OFF + (size_t)BMWORDS * 4) {
        __hip_bfloat16* wb = (__hip_bfloat16*)d_ws;
        uint32_t* bm = (uint32_t*)((char*)d_ws + BM_OFF);

        wconv_kernel<<<(NIH + NHH + 255) / 256, 256, 0, stream>>>(Wih, Whh, wb);
        bm_zero_kernel<<<(BMWORDS + 255) / 256, 256, 0, stream>>>(bm, BMWORDS);
        bm_set_kernel<<<(U + 255) / 256, 256, 0, stream>>>(ids, bm, U);

        gru_stream_kernel<true><<<nblocks, 512, 0, stream>>>(
            memory, ids, msgs, ts, Wih, Whh, bih, bhh,
            wb, wb + NIH, out_mem, out_lu, U);

        copy_skip_kernel<<<8192, 256, 0, stream>>>((const f32x4*)memory, last_update,
                                                   (f32x4*)out_mem, out_lu, bm, NN);
    } else {
        int n_mem4 = NN * MEM_DIM / 4;
        int n_tot4 = n_mem4 + NN / 4;
        copy_all_kernel<<<8192, 256, 0, stream>>>((const f32x4*)memory,
                                                  (const f32x4*)last_update,
                                                  (f32x4*)d_out, n_mem4, n_tot4);
        gru_stream_kernel<false><<<nblocks, 512, 0, stream>>>(
            memory, ids, msgs, ts, Wih, Whh, bih, bhh,
            nullptr, nullptr, out_mem, out_lu, U);
    }
}